// Round 1
// baseline (279.524 us; speedup 1.0000x reference)
//
#include <hip/hip_runtime.h>
#include <stdint.h>

typedef __bf16 bf16x8 __attribute__((ext_vector_type(8)));
typedef float  f32x16 __attribute__((ext_vector_type(16)));
typedef float  f32x4t __attribute__((ext_vector_type(4)));
typedef unsigned int u32x2 __attribute__((ext_vector_type(2)));

// ---- ws layout (bytes) ----
#define WS_W1E 0            // 256*64 bf16  = 32768 B
#define WS_W2  32768        // 256*256 bf16 = 131072 B
#define WS_R   163840       // 4*256*256 f32 = 1 MiB   R_t[b][n][o] (incl. b1)
#define WS_CC  1212416      // 4*256*256 f32 = 1 MiB   C_t[b][m][o]

// ---------------- pre-kernel 1: weights -> bf16 ----------------
__global__ void prep_weights(const float* __restrict__ W1, const float* __restrict__ W2,
                             __bf16* __restrict__ w1e, __bf16* __restrict__ w2b) {
    int i = blockIdx.x * 256 + threadIdx.x;
    if (i < 256 * 64) {
        int o = i >> 6, e = i & 63;
        w1e[i] = (__bf16)W1[o * 320 + e];
    }
    int j = i - 256 * 64;
    if (j >= 0 && j < 256 * 256) w2b[j] = (__bf16)W2[j];
}

// ---------------- pre-kernel 2: R/C rank-1 terms (fp32, exact) ----------------
// R_t[b][j][o] = b1[o] + sum_c W1[o][64+c]  * node[b][c][j]
// C_t[b][j][o] =         sum_c W1[o][192+c] * node[b][c][j]
__global__ void prep_rc(const float* __restrict__ W1, const float* __restrict__ b1,
                        const float* __restrict__ node, float* __restrict__ Rt,
                        float* __restrict__ Ct) {
    int blk = blockIdx.x;            // 0..1023 = b(4) x jb(16) x ob(16)
    int b  = blk >> 8;
    int jb = (blk >> 4) & 15;
    int ob = blk & 15;
    int oi = threadIdx.x & 15, ji = threadIdx.x >> 4;
    int o = ob * 16 + oi, j = jb * 16 + ji;
    float aR = 0.f, aC = 0.f;
    const float* wr = W1 + o * 320 + 64;
    const float* wc = W1 + o * 320 + 192;
    const float* nd = node + (b * 128) * 256 + j;
#pragma unroll 4
    for (int c = 0; c < 128; ++c) {
        float nv = nd[c * 256];
        aR = fmaf(wr[c], nv, aR);
        aC = fmaf(wc[c], nv, aC);
    }
    int idx = ((b * 256 + j) << 8) + o;
    Rt[idx] = aR + b1[o];
    Ct[idx] = aC;
}

// ---------------- main fused kernel ----------------
// Persistent: 512 blocks x 256 thr (4 waves). Block tile = 64 pixels of row n.
// Wave owns 64 output channels (2 blocks of 32). 32x32x16 bf16 MFMA.
__device__ inline f32x16 zero16() {
    f32x16 v;
#pragma unroll
    for (int i = 0; i < 16; ++i) v[i] = 0.f;
    return v;
}

__global__ __launch_bounds__(256, 2) void fused_main(
    const float* __restrict__ edge, const __bf16* __restrict__ w1e,
    const __bf16* __restrict__ w2, const float* __restrict__ Rt,
    const float* __restrict__ Ct, const float* __restrict__ b2,
    const float* __restrict__ W3, const float* __restrict__ b3,
    float* __restrict__ out) {
    // LDS: edge tile [64 m][36 dw] (64 e bf16 + pad, 16B-aligned rows, odd dw/4 stride)
    //      h1 tile  [64 pix][140 dw] (256 ch bf16, 560B row: b128-aligned + spread)
    //      partials [64 pix][9]
    __shared__ unsigned int lds_e[64 * 36];
    __shared__ unsigned int lds_h1[64 * 140];
    __shared__ float lds_p[64 * 9];

    const int tid  = threadIdx.x;
    const int wid  = tid >> 6;
    const int lane = tid & 63;
    const int p31  = lane & 31;
    const int hi   = lane >> 5;
    const int obase = wid * 64;

    // ---- persistent A fragments: W2 (128 VGPR) + W1e (16 VGPR) ----
    bf16x8 A2[2][16];
#pragma unroll
    for (int mb = 0; mb < 2; ++mb)
#pragma unroll
        for (int ks = 0; ks < 16; ++ks)
            A2[mb][ks] = *(const bf16x8*)(w2 + (obase + mb * 32 + p31) * 256 + ks * 16 + hi * 8);
    bf16x8 A1[2][4];
#pragma unroll
    for (int mb = 0; mb < 2; ++mb)
#pragma unroll
        for (int ks = 0; ks < 4; ++ks)
            A1[mb][ks] = *(const bf16x8*)(w1e + (obase + mb * 32 + p31) * 64 + ks * 16 + hi * 8);

    for (int it = 0; it < 8; ++it) {
        int tile = blockIdx.x * 8 + it;         // 4096 tiles total
        int b  = tile >> 10;
        int n  = (tile >> 2) & 255;
        int m0 = (tile & 3) << 6;

        // ---- stage edge tile: transpose [e][m] -> [m][e] bf16 ----
        {
            const float4* eg = (const float4*)edge;
#pragma unroll
            for (int r = 0; r < 2; ++r) {
                int task = r * 256 + tid;
                int a  = task & 15;             // m-group (4 pixels)
                int ep = task >> 4;             // e-pair 0..31
                int f4 = (b * 64 + ep * 2) * 16384 + n * 64 + (m0 >> 2) + a;
                float4 v0 = eg[f4];
                float4 v1 = eg[f4 + 16384];
                const float* p0 = (const float*)&v0;
                const float* p1 = (const float*)&v1;
#pragma unroll
                for (int i = 0; i < 4; ++i) {
                    union { __bf16 h[2]; unsigned int u; } t;
                    t.h[0] = (__bf16)p0[i];
                    t.h[1] = (__bf16)p1[i];
                    lds_e[(a * 4 + i) * 36 + ep] = t.u;
                }
            }
        }
        __syncthreads();

        // ---- layer 1: a1 = W1e(64K) @ edge ----
        f32x16 acc1[2][2];
        acc1[0][0] = zero16(); acc1[0][1] = zero16();
        acc1[1][0] = zero16(); acc1[1][1] = zero16();
#pragma unroll
        for (int ks = 0; ks < 4; ++ks) {
            bf16x8 B1[2];
#pragma unroll
            for (int nb = 0; nb < 2; ++nb)
                B1[nb] = *(const bf16x8*)&lds_e[(nb * 32 + p31) * 36 + ks * 8 + hi * 4];
#pragma unroll
            for (int mb = 0; mb < 2; ++mb) {
                acc1[mb][0] = __builtin_amdgcn_mfma_f32_32x32x16_bf16(A1[mb][ks], B1[0], acc1[mb][0], 0, 0, 0);
                acc1[mb][1] = __builtin_amdgcn_mfma_f32_32x32x16_bf16(A1[mb][ks], B1[1], acc1[mb][1], 0, 0, 0);
            }
        }

        // ---- layer-1 epilogue: + R[n] + C[m], relu, bf16 -> lds_h1 ----
        const int nRow = (b * 256 + n) << 8;
#pragma unroll
        for (int mb = 0; mb < 2; ++mb) {
#pragma unroll
            for (int rg = 0; rg < 4; ++rg) {
                int och = obase + mb * 32 + 8 * rg + 4 * hi;   // 4 consecutive channels
                f32x4t Rv = *(const f32x4t*)(Rt + nRow + och);
#pragma unroll
                for (int nb = 0; nb < 2; ++nb) {
                    int pix = nb * 32 + p31;
                    f32x4t Cv = *(const f32x4t*)(Ct + ((b * 256 + m0 + pix) << 8) + och);
                    union { __bf16 h[4]; u32x2 u; } t;
#pragma unroll
                    for (int rr = 0; rr < 4; ++rr) {
                        float v = acc1[mb][nb][rg * 4 + rr] + Rv[rr] + Cv[rr];
                        t.h[rr] = (__bf16)fmaxf(v, 0.f);
                    }
                    *(u32x2*)&lds_h1[pix * 140 + (och >> 1)] = t.u;
                }
            }
        }
        __syncthreads();

        // ---- layer 2: a2 = W2(256K) @ h1 ----
        f32x16 acc2[2][2];
        acc2[0][0] = zero16(); acc2[0][1] = zero16();
        acc2[1][0] = zero16(); acc2[1][1] = zero16();
#pragma unroll
        for (int ks = 0; ks < 16; ++ks) {
            bf16x8 B2[2];
#pragma unroll
            for (int nb = 0; nb < 2; ++nb)
                B2[nb] = *(const bf16x8*)&lds_h1[(nb * 32 + p31) * 140 + ks * 8 + hi * 4];
#pragma unroll
            for (int mb = 0; mb < 2; ++mb) {
                acc2[mb][0] = __builtin_amdgcn_mfma_f32_32x32x16_bf16(A2[mb][ks], B2[0], acc2[mb][0], 0, 0, 0);
                acc2[mb][1] = __builtin_amdgcn_mfma_f32_32x32x16_bf16(A2[mb][ks], B2[1], acc2[mb][1], 0, 0, 0);
            }
        }

        // ---- layer 2/3 epilogue: +b2, relu, dot W3 (fp32) ----
        float part0 = 0.f, part1 = 0.f;
#pragma unroll
        for (int mb = 0; mb < 2; ++mb) {
#pragma unroll
            for (int rg = 0; rg < 4; ++rg) {
                int och = obase + mb * 32 + 8 * rg + 4 * hi;
                f32x4t b2v = *(const f32x4t*)(b2 + och);
                f32x4t w3v = *(const f32x4t*)(W3 + och);
#pragma unroll
                for (int rr = 0; rr < 4; ++rr) {
                    float h0 = fmaxf(acc2[mb][0][rg * 4 + rr] + b2v[rr], 0.f);
                    float h1v = fmaxf(acc2[mb][1][rg * 4 + rr] + b2v[rr], 0.f);
                    part0 = fmaf(w3v[rr], h0, part0);
                    part1 = fmaf(w3v[rr], h1v, part1);
                }
            }
        }
        lds_p[(0 * 32 + p31) * 9 + wid * 2 + hi] = part0;
        lds_p[(1 * 32 + p31) * 9 + wid * 2 + hi] = part1;
        __syncthreads();

        if (tid < 64) {
            float s = b3[0];
#pragma unroll
            for (int k = 0; k < 8; ++k) s += lds_p[tid * 9 + k];
            out[((b * 256 + n) << 8) + m0 + tid] = s;
        }
        // next-tile lds_e staging is gated by the next __syncthreads(); lds_e was
        // last read before this tile's bar2, so overwrite is safe.
    }
}

extern "C" void kernel_launch(void* const* d_in, const int* in_sizes, int n_in,
                              void* d_out, int out_size, void* d_ws, size_t ws_size,
                              hipStream_t stream) {
    const float* edge = (const float*)d_in[0];
    const float* node = (const float*)d_in[1];
    const float* W1   = (const float*)d_in[2];
    const float* b1   = (const float*)d_in[3];
    const float* W2   = (const float*)d_in[4];
    const float* b2   = (const float*)d_in[5];
    const float* W3   = (const float*)d_in[6];
    const float* b3   = (const float*)d_in[7];
    char* ws = (char*)d_ws;
    __bf16* w1e = (__bf16*)(ws + WS_W1E);
    __bf16* w2b = (__bf16*)(ws + WS_W2);
    float*  Rt  = (float*)(ws + WS_R);
    float*  Ct  = (float*)(ws + WS_CC);

    prep_weights<<<320, 256, 0, stream>>>(W1, W2, w1e, w2b);
    prep_rc<<<1024, 256, 0, stream>>>(W1, b1, node, Rt, Ct);
    fused_main<<<512, 256, 0, stream>>>(edge, w1e, w2b, Rt, Ct, b2, W3, b3, (float*)d_out);
}